// Round 10
// baseline (266.240 us; speedup 1.0000x reference)
//
#include <hip/hip_runtime.h>
#include <math.h>

#define HEADS 4
#define HID 32
#define FEAT 128
#define NCLS 32
#define NS 0.2f
#define CHUNK 4096
#define BSTRIDE 12288

__device__ __forceinline__ unsigned short f2bf(float x) {
    unsigned u = __float_as_uint(x);
    unsigned r = (u + 0x7FFFu + ((u >> 16) & 1u)) >> 16;
    return (unsigned short)r;
}
__device__ __forceinline__ float2 bf2x2(unsigned u) {
    float2 r;
    r.x = __uint_as_float(u << 16);
    r.y = __uint_as_float(u & 0xFFFF0000u);
    return r;
}

__device__ __forceinline__ void scan256(int* arr, int tid, int* wsum) {
    int v = arr[tid];
    int incl = v;
    #pragma unroll
    for (int off = 1; off < 64; off <<= 1) {
        int t = __shfl_up(incl, off, 64);
        if ((tid & 63) >= off) incl += t;
    }
    int wid = tid >> 6;
    if ((tid & 63) == 63) wsum[wid] = incl;
    __syncthreads();
    int wpre = 0;
    #pragma unroll
    for (int w = 0; w < 3; ++w) if (w < wid) wpre += wsum[w];
    arr[tid] = wpre + incl - v;
    __syncthreads();
}

// ---------------- cursor init ----------------
__global__ __launch_bounds__(256) void cursor_init_kernel(int* __restrict__ gcursor) {
    gcursor[threadIdx.x] = threadIdx.x * BSTRIDE;
}

// ---------------- FAT kernel: gemm1 blocks then bin blocks ----------------
union SMem {
    struct { float xs[64][32]; float ws[32][128]; } g;
    struct { int hist[256]; int lcur[256]; int rbase[256]; int wsum[4];
             unsigned int stage[CHUNK]; unsigned short sbkt[CHUNK]; } b;
};

__device__ void gemm1_body(SMem& sm, int bid,
    const float* __restrict__ x, const float* __restrict__ W1,
    const float* __restrict__ as1, const float* __restrict__ ad1,
    unsigned short* __restrict__ h1b, float* __restrict__ a1s,
    float* __restrict__ a1d, int N) {
    int tid = threadIdx.x;
    int tx = tid & 31;
    int ty = tid >> 5;
    int row0 = bid * 64;
    float4 acc[8];
    #pragma unroll
    for (int r = 0; r < 8; ++r) acc[r] = make_float4(0.f, 0.f, 0.f, 0.f);

    for (int k0 = 0; k0 < FEAT; k0 += 32) {
        __syncthreads();
        #pragma unroll
        for (int i = tid; i < 512; i += 256) {
            int r = i >> 3, c4 = i & 7;
            int n = row0 + r;
            float4 v = (n < N) ? *(const float4*)(x + (size_t)n * FEAT + k0 + c4 * 4)
                               : make_float4(0.f, 0.f, 0.f, 0.f);
            *(float4*)&sm.g.xs[r][c4 * 4] = v;
        }
        #pragma unroll
        for (int i = tid; i < 1024; i += 256) {
            int k = i >> 5, c4 = i & 31;
            *(float4*)&sm.g.ws[k][c4 * 4] =
                *(const float4*)(W1 + (size_t)(k0 + k) * FEAT + c4 * 4);
        }
        __syncthreads();

        for (int k = 0; k < 32; k += 4) {
            float4 xv[8];
            #pragma unroll
            for (int r = 0; r < 8; ++r) xv[r] = *(float4*)&sm.g.xs[ty * 8 + r][k];
            #pragma unroll
            for (int kk = 0; kk < 4; ++kk) {
                float4 wv = *(float4*)&sm.g.ws[k + kk][tx * 4];
                #pragma unroll
                for (int r = 0; r < 8; ++r) {
                    float xr = (kk == 0) ? xv[r].x : (kk == 1) ? xv[r].y
                             : (kk == 2) ? xv[r].z : xv[r].w;
                    acc[r].x += xr * wv.x;
                    acc[r].y += xr * wv.y;
                    acc[r].z += xr * wv.z;
                    acc[r].w += xr * wv.w;
                }
            }
        }
    }
    int hd = tx >> 3;
    float4 av = *(const float4*)(as1 + tx * 4);
    float4 dv = *(const float4*)(ad1 + tx * 4);
    #pragma unroll
    for (int r = 0; r < 8; ++r) {
        int n = row0 + ty * 8 + r;
        if (n >= N) break;
        unsigned int lo = (unsigned)f2bf(acc[r].x) | ((unsigned)f2bf(acc[r].y) << 16);
        unsigned int hi = (unsigned)f2bf(acc[r].z) | ((unsigned)f2bf(acc[r].w) << 16);
        uint2 pk; pk.x = lo; pk.y = hi;
        *(uint2*)(h1b + (size_t)n * FEAT + tx * 4) = pk;
        float vs = acc[r].x * av.x + acc[r].y * av.y + acc[r].z * av.z + acc[r].w * av.w;
        float vd = acc[r].x * dv.x + acc[r].y * dv.y + acc[r].z * dv.z + acc[r].w * dv.w;
        #pragma unroll
        for (int off = 4; off; off >>= 1) {
            vs += __shfl_down(vs, off);
            vd += __shfl_down(vd, off);
        }
        if ((tx & 7) == 0) {
            a1s[n * HEADS + hd] = vs;
            a1d[n * HEADS + hd] = vd;
        }
    }
}

__device__ void bin_body(SMem& sm, int bid,
    const int* __restrict__ ei, int E, int ET,
    int* __restrict__ gcursor, unsigned int* __restrict__ binned) {
    int tid = threadIdx.x;
    int cb = bid * CHUNK;
    int sv[16], dv[16];
    sm.b.hist[tid] = 0;
    __syncthreads();
    #pragma unroll
    for (int r = 0; r < 16; ++r) {
        int i = cb + r * 256 + tid;
        int s = 0, d = -1;
        if (i < ET) {
            if (i < E) { s = ei[i]; d = ei[E + i]; }
            else { s = d = i - E; }
            atomicAdd(&sm.b.hist[d >> 8], 1);
        }
        sv[r] = s; dv[r] = d;
    }
    __syncthreads();
    int c = sm.b.hist[tid];
    sm.b.rbase[tid] = c ? atomicAdd(&gcursor[tid], c) : 0;
    scan256(sm.b.hist, tid, sm.b.wsum);
    sm.b.lcur[tid] = sm.b.hist[tid];
    __syncthreads();
    #pragma unroll
    for (int r = 0; r < 16; ++r) {
        if (dv[r] >= 0) {
            int b = dv[r] >> 8;
            int slot = atomicAdd(&sm.b.lcur[b], 1);
            sm.b.stage[slot] = (unsigned int)sv[r] | ((unsigned int)(dv[r] & 255) << 16);
            sm.b.sbkt[slot] = (unsigned short)b;
        }
    }
    __syncthreads();
    int nval = ET - cb; if (nval > CHUNK) nval = CHUNK;
    for (int j = tid; j < nval; j += 256) {
        int b = sm.b.sbkt[j];
        binned[sm.b.rbase[b] + (j - sm.b.hist[b])] = sm.b.stage[j];
    }
}

__global__ __launch_bounds__(256) void fat1_kernel(
    int g1blocks,
    const float* __restrict__ x, const float* __restrict__ W1,
    const float* __restrict__ as1, const float* __restrict__ ad1,
    unsigned short* __restrict__ h1b, float* __restrict__ a1s,
    float* __restrict__ a1d, int N,
    const int* __restrict__ ei, int E, int ET,
    int* __restrict__ gcursor, unsigned int* __restrict__ binned) {
    __shared__ SMem sm;
    if ((int)blockIdx.x < g1blocks)
        gemm1_body(sm, blockIdx.x, x, W1, as1, ad1, h1b, a1s, a1d, N);
    else
        bin_body(sm, blockIdx.x - g1blocks, ei, E, ET, gcursor, binned);
}

// ---------------- csr: per-bucket compaction ----------------
__global__ __launch_bounds__(256) void csr_kernel(
    unsigned int* __restrict__ binned, const int* __restrict__ gcursor,
    int* __restrict__ offs, int* __restrict__ oend, int N) {
    __shared__ int ncnt[256];
    __shared__ int ncur[256];
    __shared__ int wsum[4];
    __shared__ unsigned short lcsr[BSTRIDE];
    int b = blockIdx.x, tid = threadIdx.x;
    int base = b * BSTRIDE;
    int cnt = gcursor[b] - base;
    if (cnt > BSTRIDE) cnt = BSTRIDE;
    ncnt[tid] = 0;
    __syncthreads();
    for (int j = tid; j < cnt; j += 256)
        atomicAdd(&ncnt[(binned[base + j] >> 16) & 255], 1);
    __syncthreads();
    int c = ncnt[tid];
    __syncthreads();
    scan256(ncnt, tid, wsum);
    int pre = ncnt[tid];
    int g = (b << 8) + tid;
    if (g < N) { offs[g] = base + pre; oend[g] = base + pre + c; }
    ncur[tid] = pre;
    __syncthreads();
    for (int j = tid; j < cnt; j += 256) {
        unsigned int u = binned[base + j];
        int p = atomicAdd(&ncur[(u >> 16) & 255], 1);
        lcsr[p] = (unsigned short)(u & 0xFFFFu);
    }
    __syncthreads();
    for (int j = tid; j < cnt; j += 256)
        binned[base + j] = (unsigned int)lcsr[j];
}

// ---------------- Layer 1 aggregation: staged + block barrier ----------------
__global__ __launch_bounds__(256) void agg1_kernel(
    const unsigned short* __restrict__ h1b, const float* __restrict__ a1s,
    const float* __restrict__ a1d, const int* __restrict__ offs,
    const int* __restrict__ oend, const int* __restrict__ csr,
    const float* __restrict__ b1, float* __restrict__ hout, int N) {
    __shared__ float exs[4][64][4];   // [wave][edge][head]
    __shared__ int   sN[4][64];
    int wv = threadIdx.x >> 6;
    int d = blockIdx.x * 4 + wv;
    bool active = (d < N);
    int lane = threadIdx.x & 63;
    int beg = 0, end = 0, deg = 0;
    float4 adv = make_float4(0.f, 0.f, 0.f, 0.f);
    if (active) {
        beg = offs[d]; end = oend[d]; deg = end - beg;
        adv = *(const float4*)(a1d + d * 4);
    }

    // ---- staging phase (every thread writes its slot; zeros pad) ----
    float al0 = 0.f, al1 = 0.f, al2 = 0.f, al3 = 0.f;
    int s_e = 0;
    if (active && lane < deg && deg <= 64) {
        s_e = csr[beg + lane];
        float4 as = *(const float4*)(a1s + s_e * 4);
        float e0 = as.x + adv.x; e0 = e0 >= 0.f ? e0 : NS * e0; al0 = __expf(e0);
        float e1 = as.y + adv.y; e1 = e1 >= 0.f ? e1 : NS * e1; al1 = __expf(e1);
        float e2 = as.z + adv.z; e2 = e2 >= 0.f ? e2 : NS * e2; al2 = __expf(e2);
        float e3 = as.w + adv.w; e3 = e3 >= 0.f ? e3 : NS * e3; al3 = __expf(e3);
    }
    sN[wv][lane] = s_e;
    *(float4*)&exs[wv][lane][0] = make_float4(al0, al1, al2, al3);
    __syncthreads();          // ALL 256 threads reach this, no returns above
    if (!active) return;

    int q = lane >> 4, sub = lane & 15;
    int cl = sub * 8;
    int h3 = sub >> 2;
    float2 c0 = {0.f, 0.f}, c1 = {0.f, 0.f}, c2 = {0.f, 0.f}, c3 = {0.f, 0.f};
    float inv;

    if (deg <= 64) {
        float dn0 = al0, dn1 = al1, dn2 = al2, dn3 = al3;
        #pragma unroll
        for (int off = 32; off; off >>= 1) {
            dn0 += __shfl_xor(dn0, off);
            dn1 += __shfl_xor(dn1, off);
            dn2 += __shfl_xor(dn2, off);
            dn3 += __shfl_xor(dn3, off);
        }
        float dnh = (h3 == 0) ? dn0 : (h3 == 1) ? dn1 : (h3 == 2) ? dn2 : dn3;
        inv = 1.0f / (dnh + 1e-16f);
        for (int e = q; e < deg; e += 16) {
            int e1i = e + 4, e2i = e + 8, e3i = e + 12;
            int s0 = sN[wv][e],   s1 = sN[wv][e1i];
            int s2 = sN[wv][e2i], s3 = sN[wv][e3i];
            float a0 = exs[wv][e][h3],   a1 = exs[wv][e1i][h3];
            float a2 = exs[wv][e2i][h3], a3 = exs[wv][e3i][h3];
            uint4 A = *(const uint4*)(h1b + (size_t)s0 * FEAT + cl);
            uint4 B = *(const uint4*)(h1b + (size_t)s1 * FEAT + cl);
            uint4 C = *(const uint4*)(h1b + (size_t)s2 * FEAT + cl);
            uint4 D = *(const uint4*)(h1b + (size_t)s3 * FEAT + cl);
            float2 t;
            t = bf2x2(A.x); c0.x += t.x * a0; c0.y += t.y * a0;
            t = bf2x2(A.y); c1.x += t.x * a0; c1.y += t.y * a0;
            t = bf2x2(A.z); c2.x += t.x * a0; c2.y += t.y * a0;
            t = bf2x2(A.w); c3.x += t.x * a0; c3.y += t.y * a0;
            t = bf2x2(B.x); c0.x += t.x * a1; c0.y += t.y * a1;
            t = bf2x2(B.y); c1.x += t.x * a1; c1.y += t.y * a1;
            t = bf2x2(B.z); c2.x += t.x * a1; c2.y += t.y * a1;
            t = bf2x2(B.w); c3.x += t.x * a1; c3.y += t.y * a1;
            t = bf2x2(C.x); c0.x += t.x * a2; c0.y += t.y * a2;
            t = bf2x2(C.y); c1.x += t.x * a2; c1.y += t.y * a2;
            t = bf2x2(C.z); c2.x += t.x * a2; c2.y += t.y * a2;
            t = bf2x2(C.w); c3.x += t.x * a2; c3.y += t.y * a2;
            t = bf2x2(D.x); c0.x += t.x * a3; c0.y += t.y * a3;
            t = bf2x2(D.y); c1.x += t.x * a3; c1.y += t.y * a3;
            t = bf2x2(D.z); c2.x += t.x * a3; c2.y += t.y * a3;
            t = bf2x2(D.w); c3.x += t.x * a3; c3.y += t.y * a3;
        }
    } else {
        float adh = (h3 == 0) ? adv.x : (h3 == 1) ? adv.y : (h3 == 2) ? adv.z : adv.w;
        float dn = 0.f;
        for (int i = beg; i < end; i += 16) {
            int i0 = i + q, i1 = i + 4 + q, i2 = i + 8 + q, i3 = i + 12 + q;
            bool v0 = i0 < end, v1 = i1 < end, v2 = i2 < end, v3 = i3 < end;
            int s0 = csr[v0 ? i0 : beg];
            int s1 = csr[v1 ? i1 : beg];
            int s2 = csr[v2 ? i2 : beg];
            int s3 = csr[v3 ? i3 : beg];
            float e0 = a1s[s0 * 4 + h3] + adh; e0 = e0 >= 0.f ? e0 : NS * e0;
            float e1 = a1s[s1 * 4 + h3] + adh; e1 = e1 >= 0.f ? e1 : NS * e1;
            float e2 = a1s[s2 * 4 + h3] + adh; e2 = e2 >= 0.f ? e2 : NS * e2;
            float e3 = a1s[s3 * 4 + h3] + adh; e3 = e3 >= 0.f ? e3 : NS * e3;
            float al0f = v0 ? __expf(e0) : 0.f;
            float al1f = v1 ? __expf(e1) : 0.f;
            float al2f = v2 ? __expf(e2) : 0.f;
            float al3f = v3 ? __expf(e3) : 0.f;
            dn += (al0f + al1f) + (al2f + al3f);
            uint4 A = *(const uint4*)(h1b + (size_t)s0 * FEAT + cl);
            uint4 B = *(const uint4*)(h1b + (size_t)s1 * FEAT + cl);
            uint4 C = *(const uint4*)(h1b + (size_t)s2 * FEAT + cl);
            uint4 D = *(const uint4*)(h1b + (size_t)s3 * FEAT + cl);
            float2 t;
            t = bf2x2(A.x); c0.x += t.x * al0f; c0.y += t.y * al0f;
            t = bf2x2(A.y); c1.x += t.x * al0f; c1.y += t.y * al0f;
            t = bf2x2(A.z); c2.x += t.x * al0f; c2.y += t.y * al0f;
            t = bf2x2(A.w); c3.x += t.x * al0f; c3.y += t.y * al0f;
            t = bf2x2(B.x); c0.x += t.x * al1f; c0.y += t.y * al1f;
            t = bf2x2(B.y); c1.x += t.x * al1f; c1.y += t.y * al1f;
            t = bf2x2(B.z); c2.x += t.x * al1f; c2.y += t.y * al1f;
            t = bf2x2(B.w); c3.x += t.x * al1f; c3.y += t.y * al1f;
            t = bf2x2(C.x); c0.x += t.x * al2f; c0.y += t.y * al2f;
            t = bf2x2(C.y); c1.x += t.x * al2f; c1.y += t.y * al2f;
            t = bf2x2(C.z); c2.x += t.x * al2f; c2.y += t.y * al2f;
            t = bf2x2(C.w); c3.x += t.x * al2f; c3.y += t.y * al2f;
            t = bf2x2(D.x); c0.x += t.x * al3f; c0.y += t.y * al3f;
            t = bf2x2(D.y); c1.x += t.x * al3f; c1.y += t.y * al3f;
            t = bf2x2(D.z); c2.x += t.x * al3f; c2.y += t.y * al3f;
            t = bf2x2(D.w); c3.x += t.x * al3f; c3.y += t.y * al3f;
        }
        dn += __shfl_xor(dn, 16);
        dn += __shfl_xor(dn, 32);
        inv = 1.0f / (dn + 1e-16f);
    }
    #pragma unroll
    for (int off = 32; off >= 16; off >>= 1) {
        c0.x += __shfl_xor(c0.x, off); c0.y += __shfl_xor(c0.y, off);
        c1.x += __shfl_xor(c1.x, off); c1.y += __shfl_xor(c1.y, off);
        c2.x += __shfl_xor(c2.x, off); c2.y += __shfl_xor(c2.y, off);
        c3.x += __shfl_xor(c3.x, off); c3.y += __shfl_xor(c3.y, off);
    }
    if (q == 0) {
        float4 b0 = *(const float4*)(b1 + cl);
        float4 b4 = *(const float4*)(b1 + cl + 4);
        float4 o0, o1;
        o0.x = c0.x * inv + b0.x; o0.x = o0.x > 0.f ? o0.x : 0.f;
        o0.y = c0.y * inv + b0.y; o0.y = o0.y > 0.f ? o0.y : 0.f;
        o0.z = c1.x * inv + b0.z; o0.z = o0.z > 0.f ? o0.z : 0.f;
        o0.w = c1.y * inv + b0.w; o0.w = o0.w > 0.f ? o0.w : 0.f;
        o1.x = c2.x * inv + b4.x; o1.x = o1.x > 0.f ? o1.x : 0.f;
        o1.y = c2.y * inv + b4.y; o1.y = o1.y > 0.f ? o1.y : 0.f;
        o1.z = c3.x * inv + b4.z; o1.z = o1.z > 0.f ? o1.z : 0.f;
        o1.w = c3.y * inv + b4.w; o1.w = o1.w > 0.f ? o1.w : 0.f;
        *(float4*)(hout + (size_t)d * FEAT + cl) = o0;
        *(float4*)(hout + (size_t)d * FEAT + cl + 4) = o1;
    }
}

// ---------------- Layer 2 GEMM (unchanged) ----------------
__global__ __launch_bounds__(256) void gemm2_kernel(
    const float* __restrict__ h, const float* __restrict__ W2,
    const float* __restrict__ as2, const float* __restrict__ ad2,
    unsigned short* __restrict__ g2b, float* __restrict__ a2s,
    float* __restrict__ a2d, int N) {
    __shared__ float xs[128][33];
    __shared__ float ws[FEAT][NCLS];
    int tid = threadIdx.x;
    int tx = tid & 7;
    int ty = tid >> 3;
    int row0 = blockIdx.x * 128;

    #pragma unroll
    for (int i = tid; i < FEAT * NCLS / 4; i += 256) {
        int k = i >> 3, c4 = i & 7;
        *(float4*)&ws[k][c4 * 4] = *(const float4*)(W2 + (size_t)k * NCLS + c4 * 4);
    }

    float4 acc[4];
    #pragma unroll
    for (int r = 0; r < 4; ++r) acc[r] = make_float4(0.f, 0.f, 0.f, 0.f);

    for (int k0 = 0; k0 < FEAT; k0 += 32) {
        __syncthreads();
        #pragma unroll
        for (int i = tid; i < 1024; i += 256) {
            int r = i >> 3, c4 = i & 7;
            int n = row0 + r;
            float4 v = (n < N) ? *(const float4*)(h + (size_t)n * FEAT + k0 + c4 * 4)
                               : make_float4(0.f, 0.f, 0.f, 0.f);
            xs[r][c4 * 4 + 0] = v.x;
            xs[r][c4 * 4 + 1] = v.y;
            xs[r][c4 * 4 + 2] = v.z;
            xs[r][c4 * 4 + 3] = v.w;
        }
        __syncthreads();

        for (int k = 0; k < 32; k += 4) {
            #pragma unroll
            for (int kk = 0; kk < 4; ++kk) {
                float4 wv = *(float4*)&ws[k0 + k + kk][tx * 4];
                #pragma unroll
                for (int r = 0; r < 4; ++r) {
                    float xr = xs[ty * 4 + r][k + kk];
                    acc[r].x += xr * wv.x;
                    acc[r].y += xr * wv.y;
                    acc[r].z += xr * wv.z;
                    acc[r].w += xr * wv.w;
                }
            }
        }
    }
    float4 av = *(const float4*)(as2 + tx * 4);
    float4 dv = *(const float4*)(ad2 + tx * 4);
    #pragma unroll
    for (int r = 0; r < 4; ++r) {
        int n = row0 + ty * 4 + r;
        if (n >= N) break;
        unsigned int lo = (unsigned)f2bf(acc[r].x) | ((unsigned)f2bf(acc[r].y) << 16);
        unsigned int hi = (unsigned)f2bf(acc[r].z) | ((unsigned)f2bf(acc[r].w) << 16);
        uint2 pk; pk.x = lo; pk.y = hi;
        *(uint2*)(g2b + (size_t)n * NCLS + tx * 4) = pk;
        float vs = acc[r].x * av.x + acc[r].y * av.y + acc[r].z * av.z + acc[r].w * av.w;
        float vd = acc[r].x * dv.x + acc[r].y * dv.y + acc[r].z * dv.z + acc[r].w * dv.w;
        #pragma unroll
        for (int off = 4; off; off >>= 1) {
            vs += __shfl_down(vs, off);
            vd += __shfl_down(vd, off);
        }
        if (tx == 0) { a2s[n] = vs; a2d[n] = vd; }
    }
}

// ---------------- Layer 2 aggregation (R8 proven version) ----------------
__global__ __launch_bounds__(256) void agg2_kernel(
    const unsigned short* __restrict__ g2b, const float* __restrict__ a2s,
    const float* __restrict__ a2d, const int* __restrict__ offs,
    const int* __restrict__ oend, const int* __restrict__ csr,
    const float* __restrict__ b2, float* __restrict__ out, int N) {
    int d = blockIdx.x * 4 + (threadIdx.x >> 6);
    if (d >= N) return;
    int lane = threadIdx.x & 63;
    int beg = offs[d], end = oend[d];
    float ad = a2d[d];

    int q = lane >> 4, sub = lane & 15;
    int ch2 = sub * 2;
    float dn = 0.f;
    float2 ac = {0.f, 0.f};
    for (int i = beg; i < end; i += 16) {
        int i0 = i + q, i1 = i + 4 + q, i2 = i + 8 + q, i3 = i + 12 + q;
        bool v0 = i0 < end, v1 = i1 < end, v2 = i2 < end, v3 = i3 < end;
        int s0 = csr[v0 ? i0 : beg];
        int s1 = csr[v1 ? i1 : beg];
        int s2 = csr[v2 ? i2 : beg];
        int s3 = csr[v3 ? i3 : beg];
        float e0 = a2s[s0] + ad; e0 = e0 >= 0.f ? e0 : NS * e0;
        float e1 = a2s[s1] + ad; e1 = e1 >= 0.f ? e1 : NS * e1;
        float e2 = a2s[s2] + ad; e2 = e2 >= 0.f ? e2 : NS * e2;
        float e3 = a2s[s3] + ad; e3 = e3 >= 0.f ? e3 : NS * e3;
        float al0 = v0 ? __expf(e0) : 0.f;
        float al1 = v1 ? __expf(e1) : 0.f;
        float al2 = v2 ? __expf(e2) : 0.f;
        float al3 = v3 ? __expf(e3) : 0.f;
        dn += (al0 + al1) + (al2 + al3);
        unsigned int A = *(const unsigned int*)(g2b + (size_t)s0 * NCLS + ch2);
        unsigned int B = *(const unsigned int*)(g2b + (size_t)s1 * NCLS + ch2);
        unsigned int C = *(const unsigned int*)(g2b + (size_t)s2 * NCLS + ch2);
        unsigned int D = *(const unsigned int*)(g2b + (size_t)s3 * NCLS + ch2);
        float2 t;
        t = bf2x2(A); ac.x += t.x * al0; ac.y += t.y * al0;
        t = bf2x2(B); ac.x += t.x * al1; ac.y += t.y * al1;
        t = bf2x2(C); ac.x += t.x * al2; ac.y += t.y * al2;
        t = bf2x2(D); ac.x += t.x * al3; ac.y += t.y * al3;
    }
    dn += __shfl_xor(dn, 16);
    dn += __shfl_xor(dn, 32);
    #pragma unroll
    for (int off = 32; off >= 16; off >>= 1) {
        ac.x += __shfl_xor(ac.x, off);
        ac.y += __shfl_xor(ac.y, off);
    }
    float inv = 1.0f / (dn + 1e-16f);
    float2 bb = *(const float2*)(b2 + ch2);
    float v0 = ac.x * inv + bb.x;
    float v1 = ac.y * inv + bb.y;
    float m = fmaxf(v0, v1);
    #pragma unroll
    for (int off = 8; off; off >>= 1) m = fmaxf(m, __shfl_xor(m, off, 16));
    float e0 = __expf(v0 - m), e1 = __expf(v1 - m);
    float sm = e0 + e1;
    #pragma unroll
    for (int off = 8; off; off >>= 1) sm += __shfl_xor(sm, off, 16);
    if (q == 0) {
        float2 o; o.x = e0 / sm; o.y = e1 / sm;
        *(float2*)(out + (size_t)d * NCLS + ch2) = o;
    }
}

extern "C" void kernel_launch(void* const* d_in, const int* in_sizes, int n_in,
                              void* d_out, int out_size, void* d_ws, size_t ws_size,
                              hipStream_t stream) {
    const float* x   = (const float*)d_in[0];
    const int*   ei  = (const int*)d_in[1];
    const float* W1  = (const float*)d_in[2];
    const float* as1 = (const float*)d_in[3];
    const float* ad1 = (const float*)d_in[4];
    const float* b1  = (const float*)d_in[5];
    const float* W2  = (const float*)d_in[6];
    const float* as2 = (const float*)d_in[7];
    const float* ad2 = (const float*)d_in[8];
    const float* b2  = (const float*)d_in[9];
    float* out = (float*)d_out;

    int N = in_sizes[0] / FEAT;
    int E = in_sizes[1] / 2;
    int ET = E + N;
    int NB = (N + 255) >> 8;

    float* ws   = (float*)d_ws;
    unsigned short* h1b = (unsigned short*)ws;        // N*128 bf16
    float* hout = (float*)(h1b + (size_t)N * FEAT);   // N*128 f32
    unsigned short* g2b = (unsigned short*)(hout + (size_t)N * FEAT); // N*32 bf16
    float* a1s  = (float*)(g2b + (size_t)N * NCLS);   // N*4
    float* a1d  = a1s + (size_t)N * HEADS;            // N*4
    float* a2s  = a1d + (size_t)N * HEADS;            // N
    float* a2d  = a2s + N;                            // N
    int* offs   = (int*)(a2d + N);                    // N
    int* oend   = offs + N;                           // N
    unsigned int* binned = (unsigned int*)(oend + N); // 256*BSTRIDE (doubles as csr)
    int* gcursor = (int*)(binned + (size_t)256 * BSTRIDE); // 256

    int nchunks = (ET + CHUNK - 1) / CHUNK;
    int g1blocks = (N + 63) / 64;

    cursor_init_kernel<<<1, 256, 0, stream>>>(gcursor);
    fat1_kernel<<<g1blocks + nchunks, 256, 0, stream>>>(
        g1blocks, x, W1, as1, ad1, h1b, a1s, a1d, N, ei, E, ET, gcursor, binned);
    csr_kernel<<<NB, 256, 0, stream>>>(binned, gcursor, offs, oend, N);

    const int* csr = (const int*)binned;
    agg1_kernel<<<(N + 3) / 4, 256, 0, stream>>>(h1b, a1s, a1d, offs, oend, csr, b1, hout, N);
    gemm2_kernel<<<(N + 127) / 128, 256, 0, stream>>>(hout, W2, as2, ad2, g2b, a2s, a2d, N);
    agg2_kernel<<<(N + 3) / 4, 256, 0, stream>>>(g2b, a2s, a2d, offs, oend, csr, b2, out, N);
}

// Round 11
// 261.401 us; speedup vs baseline: 1.0185x; 1.0185x over previous
//
#include <hip/hip_runtime.h>
#include <math.h>

#define HEADS 4
#define HID 32
#define FEAT 128
#define NCLS 32
#define NS 0.2f
#define CHUNK 4096
#define BSTRIDE 12288

__device__ __forceinline__ unsigned short f2bf(float x) {
    unsigned u = __float_as_uint(x);
    unsigned r = (u + 0x7FFFu + ((u >> 16) & 1u)) >> 16;
    return (unsigned short)r;
}
__device__ __forceinline__ float2 bf2x2(unsigned u) {
    float2 r;
    r.x = __uint_as_float(u << 16);
    r.y = __uint_as_float(u & 0xFFFF0000u);
    return r;
}

__device__ __forceinline__ void scan256(int* arr, int tid, int* wsum) {
    int v = arr[tid];
    int incl = v;
    #pragma unroll
    for (int off = 1; off < 64; off <<= 1) {
        int t = __shfl_up(incl, off, 64);
        if ((tid & 63) >= off) incl += t;
    }
    int wid = tid >> 6;
    if ((tid & 63) == 63) wsum[wid] = incl;
    __syncthreads();
    int wpre = 0;
    #pragma unroll
    for (int w = 0; w < 3; ++w) if (w < wid) wpre += wsum[w];
    arr[tid] = wpre + incl - v;
    __syncthreads();
}

// ---------------- cursor init ----------------
__global__ __launch_bounds__(256) void cursor_init_kernel(int* __restrict__ gcursor) {
    gcursor[threadIdx.x] = threadIdx.x * BSTRIDE;
}

// ---------------- bin: partition edges into fixed-stride bucket regions -------
__global__ __launch_bounds__(256) void bin_kernel(
    const int* __restrict__ ei, int E, int ET,
    int* __restrict__ gcursor, unsigned int* __restrict__ binned) {
    __shared__ int hist[256];
    __shared__ int lcur[256];
    __shared__ int rbase[256];
    __shared__ int wsum[4];
    __shared__ unsigned int stage[CHUNK];
    __shared__ unsigned short sbkt[CHUNK];
    int tid = threadIdx.x;
    int cb = blockIdx.x * CHUNK;
    int sv[16], dv[16];
    hist[tid] = 0;
    __syncthreads();
    #pragma unroll
    for (int r = 0; r < 16; ++r) {
        int i = cb + r * 256 + tid;
        int s = 0, d = -1;
        if (i < ET) {
            if (i < E) { s = ei[i]; d = ei[E + i]; }
            else { s = d = i - E; }
            atomicAdd(&hist[d >> 8], 1);
        }
        sv[r] = s; dv[r] = d;
    }
    __syncthreads();
    int c = hist[tid];
    rbase[tid] = c ? atomicAdd(&gcursor[tid], c) : 0;
    scan256(hist, tid, wsum);
    lcur[tid] = hist[tid];
    __syncthreads();
    #pragma unroll
    for (int r = 0; r < 16; ++r) {
        if (dv[r] >= 0) {
            int b = dv[r] >> 8;
            int slot = atomicAdd(&lcur[b], 1);
            stage[slot] = (unsigned int)sv[r] | ((unsigned int)(dv[r] & 255) << 16);
            sbkt[slot] = (unsigned short)b;
        }
    }
    __syncthreads();
    int nval = ET - cb; if (nval > CHUNK) nval = CHUNK;
    for (int j = tid; j < nval; j += 256) {
        int b = sbkt[j];
        binned[rbase[b] + (j - hist[b])] = stage[j];
    }
}

// ---------------- csr: per-bucket compaction ----------------
__global__ __launch_bounds__(256) void csr_kernel(
    unsigned int* __restrict__ binned, const int* __restrict__ gcursor,
    int* __restrict__ offs, int* __restrict__ oend, int N) {
    __shared__ int ncnt[256];
    __shared__ int ncur[256];
    __shared__ int wsum[4];
    __shared__ unsigned short lcsr[BSTRIDE];
    int b = blockIdx.x, tid = threadIdx.x;
    int base = b * BSTRIDE;
    int cnt = gcursor[b] - base;
    if (cnt > BSTRIDE) cnt = BSTRIDE;
    ncnt[tid] = 0;
    __syncthreads();
    for (int j = tid; j < cnt; j += 256)
        atomicAdd(&ncnt[(binned[base + j] >> 16) & 255], 1);
    __syncthreads();
    int c = ncnt[tid];
    __syncthreads();
    scan256(ncnt, tid, wsum);
    int pre = ncnt[tid];
    int g = (b << 8) + tid;
    if (g < N) { offs[g] = base + pre; oend[g] = base + pre + c; }
    ncur[tid] = pre;
    __syncthreads();
    for (int j = tid; j < cnt; j += 256) {
        unsigned int u = binned[base + j];
        int p = atomicAdd(&ncur[(u >> 16) & 255], 1);
        lcsr[p] = (unsigned short)(u & 0xFFFFu);
    }
    __syncthreads();
    for (int j = tid; j < cnt; j += 256)
        binned[base + j] = (unsigned int)lcsr[j];
}

// ---------------- Layer 1 GEMM: h1b = bf16(x @ W1), fused a1s/a1d ----------------
__global__ __launch_bounds__(256) void gemm1_kernel(
    const float* __restrict__ x, const float* __restrict__ W1,
    const float* __restrict__ as1, const float* __restrict__ ad1,
    unsigned short* __restrict__ h1b, float* __restrict__ a1s,
    float* __restrict__ a1d, int N) {
    __shared__ float xs[64][32];
    __shared__ float ws[32][128];
    int tid = threadIdx.x;
    int tx = tid & 31;
    int ty = tid >> 5;
    int row0 = blockIdx.x * 64;
    float4 acc[8];
    #pragma unroll
    for (int r = 0; r < 8; ++r) acc[r] = make_float4(0.f, 0.f, 0.f, 0.f);

    for (int k0 = 0; k0 < FEAT; k0 += 32) {
        __syncthreads();
        #pragma unroll
        for (int i = tid; i < 512; i += 256) {
            int r = i >> 3, c4 = i & 7;
            int n = row0 + r;
            float4 v = (n < N) ? *(const float4*)(x + (size_t)n * FEAT + k0 + c4 * 4)
                               : make_float4(0.f, 0.f, 0.f, 0.f);
            *(float4*)&xs[r][c4 * 4] = v;
        }
        #pragma unroll
        for (int i = tid; i < 1024; i += 256) {
            int k = i >> 5, c4 = i & 31;
            *(float4*)&ws[k][c4 * 4] =
                *(const float4*)(W1 + (size_t)(k0 + k) * FEAT + c4 * 4);
        }
        __syncthreads();

        for (int k = 0; k < 32; k += 4) {
            float4 xv[8];
            #pragma unroll
            for (int r = 0; r < 8; ++r) xv[r] = *(float4*)&xs[ty * 8 + r][k];
            #pragma unroll
            for (int kk = 0; kk < 4; ++kk) {
                float4 wv = *(float4*)&ws[k + kk][tx * 4];
                #pragma unroll
                for (int r = 0; r < 8; ++r) {
                    float xr = (kk == 0) ? xv[r].x : (kk == 1) ? xv[r].y
                             : (kk == 2) ? xv[r].z : xv[r].w;
                    acc[r].x += xr * wv.x;
                    acc[r].y += xr * wv.y;
                    acc[r].z += xr * wv.z;
                    acc[r].w += xr * wv.w;
                }
            }
        }
    }
    int hd = tx >> 3;
    float4 av = *(const float4*)(as1 + tx * 4);
    float4 dv = *(const float4*)(ad1 + tx * 4);
    #pragma unroll
    for (int r = 0; r < 8; ++r) {
        int n = row0 + ty * 8 + r;
        if (n >= N) break;
        unsigned int lo = (unsigned)f2bf(acc[r].x) | ((unsigned)f2bf(acc[r].y) << 16);
        unsigned int hi = (unsigned)f2bf(acc[r].z) | ((unsigned)f2bf(acc[r].w) << 16);
        uint2 pk; pk.x = lo; pk.y = hi;
        *(uint2*)(h1b + (size_t)n * FEAT + tx * 4) = pk;
        float vs = acc[r].x * av.x + acc[r].y * av.y + acc[r].z * av.z + acc[r].w * av.w;
        float vd = acc[r].x * dv.x + acc[r].y * dv.y + acc[r].z * dv.z + acc[r].w * dv.w;
        #pragma unroll
        for (int off = 4; off; off >>= 1) {
            vs += __shfl_down(vs, off);
            vd += __shfl_down(vd, off);
        }
        if ((tx & 7) == 0) {
            a1s[n * HEADS + hd] = vs;
            a1d[n * HEADS + hd] = vd;
        }
    }
}

// ---------------- Layer 1 aggregation: staged + block barrier ----------------
__global__ __launch_bounds__(256) void agg1_kernel(
    const unsigned short* __restrict__ h1b, const float* __restrict__ a1s,
    const float* __restrict__ a1d, const int* __restrict__ offs,
    const int* __restrict__ oend, const int* __restrict__ csr,
    const float* __restrict__ b1, float* __restrict__ hout, int N) {
    __shared__ float exs[4][64][4];   // [wave][edge][head]
    __shared__ int   sN[4][64];
    int wv = threadIdx.x >> 6;
    int d = blockIdx.x * 4 + wv;
    bool active = (d < N);
    int lane = threadIdx.x & 63;
    int beg = 0, end = 0, deg = 0;
    float4 adv = make_float4(0.f, 0.f, 0.f, 0.f);
    if (active) {
        beg = offs[d]; end = oend[d]; deg = end - beg;
        adv = *(const float4*)(a1d + d * 4);
    }

    float al0 = 0.f, al1 = 0.f, al2 = 0.f, al3 = 0.f;
    int s_e = 0;
    if (active && lane < deg && deg <= 64) {
        s_e = csr[beg + lane];
        float4 as = *(const float4*)(a1s + s_e * 4);
        float e0 = as.x + adv.x; e0 = e0 >= 0.f ? e0 : NS * e0; al0 = __expf(e0);
        float e1 = as.y + adv.y; e1 = e1 >= 0.f ? e1 : NS * e1; al1 = __expf(e1);
        float e2 = as.z + adv.z; e2 = e2 >= 0.f ? e2 : NS * e2; al2 = __expf(e2);
        float e3 = as.w + adv.w; e3 = e3 >= 0.f ? e3 : NS * e3; al3 = __expf(e3);
    }
    sN[wv][lane] = s_e;
    *(float4*)&exs[wv][lane][0] = make_float4(al0, al1, al2, al3);
    __syncthreads();
    if (!active) return;

    int q = lane >> 4, sub = lane & 15;
    int cl = sub * 8;
    int h3 = sub >> 2;
    float2 c0 = {0.f, 0.f}, c1 = {0.f, 0.f}, c2 = {0.f, 0.f}, c3 = {0.f, 0.f};
    float inv;

    if (deg <= 64) {
        float dn0 = al0, dn1 = al1, dn2 = al2, dn3 = al3;
        #pragma unroll
        for (int off = 32; off; off >>= 1) {
            dn0 += __shfl_xor(dn0, off);
            dn1 += __shfl_xor(dn1, off);
            dn2 += __shfl_xor(dn2, off);
            dn3 += __shfl_xor(dn3, off);
        }
        float dnh = (h3 == 0) ? dn0 : (h3 == 1) ? dn1 : (h3 == 2) ? dn2 : dn3;
        inv = 1.0f / (dnh + 1e-16f);
        for (int e = q; e < deg; e += 16) {
            int e1i = e + 4, e2i = e + 8, e3i = e + 12;
            int s0 = sN[wv][e],   s1 = sN[wv][e1i];
            int s2 = sN[wv][e2i], s3 = sN[wv][e3i];
            float a0 = exs[wv][e][h3],   a1 = exs[wv][e1i][h3];
            float a2 = exs[wv][e2i][h3], a3 = exs[wv][e3i][h3];
            uint4 A = *(const uint4*)(h1b + (size_t)s0 * FEAT + cl);
            uint4 B = *(const uint4*)(h1b + (size_t)s1 * FEAT + cl);
            uint4 C = *(const uint4*)(h1b + (size_t)s2 * FEAT + cl);
            uint4 D = *(const uint4*)(h1b + (size_t)s3 * FEAT + cl);
            float2 t;
            t = bf2x2(A.x); c0.x += t.x * a0; c0.y += t.y * a0;
            t = bf2x2(A.y); c1.x += t.x * a0; c1.y += t.y * a0;
            t = bf2x2(A.z); c2.x += t.x * a0; c2.y += t.y * a0;
            t = bf2x2(A.w); c3.x += t.x * a0; c3.y += t.y * a0;
            t = bf2x2(B.x); c0.x += t.x * a1; c0.y += t.y * a1;
            t = bf2x2(B.y); c1.x += t.x * a1; c1.y += t.y * a1;
            t = bf2x2(B.z); c2.x += t.x * a1; c2.y += t.y * a1;
            t = bf2x2(B.w); c3.x += t.x * a1; c3.y += t.y * a1;
            t = bf2x2(C.x); c0.x += t.x * a2; c0.y += t.y * a2;
            t = bf2x2(C.y); c1.x += t.x * a2; c1.y += t.y * a2;
            t = bf2x2(C.z); c2.x += t.x * a2; c2.y += t.y * a2;
            t = bf2x2(C.w); c3.x += t.x * a2; c3.y += t.y * a2;
            t = bf2x2(D.x); c0.x += t.x * a3; c0.y += t.y * a3;
            t = bf2x2(D.y); c1.x += t.x * a3; c1.y += t.y * a3;
            t = bf2x2(D.z); c2.x += t.x * a3; c2.y += t.y * a3;
            t = bf2x2(D.w); c3.x += t.x * a3; c3.y += t.y * a3;
        }
    } else {
        float adh = (h3 == 0) ? adv.x : (h3 == 1) ? adv.y : (h3 == 2) ? adv.z : adv.w;
        float dn = 0.f;
        for (int i = beg; i < end; i += 16) {
            int i0 = i + q, i1 = i + 4 + q, i2 = i + 8 + q, i3 = i + 12 + q;
            bool v0 = i0 < end, v1 = i1 < end, v2 = i2 < end, v3 = i3 < end;
            int s0 = csr[v0 ? i0 : beg];
            int s1 = csr[v1 ? i1 : beg];
            int s2 = csr[v2 ? i2 : beg];
            int s3 = csr[v3 ? i3 : beg];
            float e0 = a1s[s0 * 4 + h3] + adh; e0 = e0 >= 0.f ? e0 : NS * e0;
            float e1 = a1s[s1 * 4 + h3] + adh; e1 = e1 >= 0.f ? e1 : NS * e1;
            float e2 = a1s[s2 * 4 + h3] + adh; e2 = e2 >= 0.f ? e2 : NS * e2;
            float e3 = a1s[s3 * 4 + h3] + adh; e3 = e3 >= 0.f ? e3 : NS * e3;
            float al0f = v0 ? __expf(e0) : 0.f;
            float al1f = v1 ? __expf(e1) : 0.f;
            float al2f = v2 ? __expf(e2) : 0.f;
            float al3f = v3 ? __expf(e3) : 0.f;
            dn += (al0f + al1f) + (al2f + al3f);
            uint4 A = *(const uint4*)(h1b + (size_t)s0 * FEAT + cl);
            uint4 B = *(const uint4*)(h1b + (size_t)s1 * FEAT + cl);
            uint4 C = *(const uint4*)(h1b + (size_t)s2 * FEAT + cl);
            uint4 D = *(const uint4*)(h1b + (size_t)s3 * FEAT + cl);
            float2 t;
            t = bf2x2(A.x); c0.x += t.x * al0f; c0.y += t.y * al0f;
            t = bf2x2(A.y); c1.x += t.x * al0f; c1.y += t.y * al0f;
            t = bf2x2(A.z); c2.x += t.x * al0f; c2.y += t.y * al0f;
            t = bf2x2(A.w); c3.x += t.x * al0f; c3.y += t.y * al0f;
            t = bf2x2(B.x); c0.x += t.x * al1f; c0.y += t.y * al1f;
            t = bf2x2(B.y); c1.x += t.x * al1f; c1.y += t.y * al1f;
            t = bf2x2(B.z); c2.x += t.x * al1f; c2.y += t.y * al1f;
            t = bf2x2(B.w); c3.x += t.x * al1f; c3.y += t.y * al1f;
            t = bf2x2(C.x); c0.x += t.x * al2f; c0.y += t.y * al2f;
            t = bf2x2(C.y); c1.x += t.x * al2f; c1.y += t.y * al2f;
            t = bf2x2(C.z); c2.x += t.x * al2f; c2.y += t.y * al2f;
            t = bf2x2(C.w); c3.x += t.x * al2f; c3.y += t.y * al2f;
            t = bf2x2(D.x); c0.x += t.x * al3f; c0.y += t.y * al3f;
            t = bf2x2(D.y); c1.x += t.x * al3f; c1.y += t.y * al3f;
            t = bf2x2(D.z); c2.x += t.x * al3f; c2.y += t.y * al3f;
            t = bf2x2(D.w); c3.x += t.x * al3f; c3.y += t.y * al3f;
        }
        dn += __shfl_xor(dn, 16);
        dn += __shfl_xor(dn, 32);
        inv = 1.0f / (dn + 1e-16f);
    }
    #pragma unroll
    for (int off = 32; off >= 16; off >>= 1) {
        c0.x += __shfl_xor(c0.x, off); c0.y += __shfl_xor(c0.y, off);
        c1.x += __shfl_xor(c1.x, off); c1.y += __shfl_xor(c1.y, off);
        c2.x += __shfl_xor(c2.x, off); c2.y += __shfl_xor(c2.y, off);
        c3.x += __shfl_xor(c3.x, off); c3.y += __shfl_xor(c3.y, off);
    }
    if (q == 0) {
        float4 b0 = *(const float4*)(b1 + cl);
        float4 b4 = *(const float4*)(b1 + cl + 4);
        float4 o0, o1;
        o0.x = c0.x * inv + b0.x; o0.x = o0.x > 0.f ? o0.x : 0.f;
        o0.y = c0.y * inv + b0.y; o0.y = o0.y > 0.f ? o0.y : 0.f;
        o0.z = c1.x * inv + b0.z; o0.z = o0.z > 0.f ? o0.z : 0.f;
        o0.w = c1.y * inv + b0.w; o0.w = o0.w > 0.f ? o0.w : 0.f;
        o1.x = c2.x * inv + b4.x; o1.x = o1.x > 0.f ? o1.x : 0.f;
        o1.y = c2.y * inv + b4.y; o1.y = o1.y > 0.f ? o1.y : 0.f;
        o1.z = c3.x * inv + b4.z; o1.z = o1.z > 0.f ? o1.z : 0.f;
        o1.w = c3.y * inv + b4.w; o1.w = o1.w > 0.f ? o1.w : 0.f;
        *(float4*)(hout + (size_t)d * FEAT + cl) = o0;
        *(float4*)(hout + (size_t)d * FEAT + cl + 4) = o1;
    }
}

// ---------------- Layer 2 GEMM ----------------
__global__ __launch_bounds__(256) void gemm2_kernel(
    const float* __restrict__ h, const float* __restrict__ W2,
    const float* __restrict__ as2, const float* __restrict__ ad2,
    unsigned short* __restrict__ g2b, float* __restrict__ a2s,
    float* __restrict__ a2d, int N) {
    __shared__ float xs[128][33];
    __shared__ float ws[FEAT][NCLS];
    int tid = threadIdx.x;
    int tx = tid & 7;
    int ty = tid >> 3;
    int row0 = blockIdx.x * 128;

    #pragma unroll
    for (int i = tid; i < FEAT * NCLS / 4; i += 256) {
        int k = i >> 3, c4 = i & 7;
        *(float4*)&ws[k][c4 * 4] = *(const float4*)(W2 + (size_t)k * NCLS + c4 * 4);
    }

    float4 acc[4];
    #pragma unroll
    for (int r = 0; r < 4; ++r) acc[r] = make_float4(0.f, 0.f, 0.f, 0.f);

    for (int k0 = 0; k0 < FEAT; k0 += 32) {
        __syncthreads();
        #pragma unroll
        for (int i = tid; i < 1024; i += 256) {
            int r = i >> 3, c4 = i & 7;
            int n = row0 + r;
            float4 v = (n < N) ? *(const float4*)(h + (size_t)n * FEAT + k0 + c4 * 4)
                               : make_float4(0.f, 0.f, 0.f, 0.f);
            xs[r][c4 * 4 + 0] = v.x;
            xs[r][c4 * 4 + 1] = v.y;
            xs[r][c4 * 4 + 2] = v.z;
            xs[r][c4 * 4 + 3] = v.w;
        }
        __syncthreads();

        for (int k = 0; k < 32; k += 4) {
            #pragma unroll
            for (int kk = 0; kk < 4; ++kk) {
                float4 wv = *(float4*)&ws[k0 + k + kk][tx * 4];
                #pragma unroll
                for (int r = 0; r < 4; ++r) {
                    float xr = xs[ty * 4 + r][k + kk];
                    acc[r].x += xr * wv.x;
                    acc[r].y += xr * wv.y;
                    acc[r].z += xr * wv.z;
                    acc[r].w += xr * wv.w;
                }
            }
        }
    }
    float4 av = *(const float4*)(as2 + tx * 4);
    float4 dv = *(const float4*)(ad2 + tx * 4);
    #pragma unroll
    for (int r = 0; r < 4; ++r) {
        int n = row0 + ty * 4 + r;
        if (n >= N) break;
        unsigned int lo = (unsigned)f2bf(acc[r].x) | ((unsigned)f2bf(acc[r].y) << 16);
        unsigned int hi = (unsigned)f2bf(acc[r].z) | ((unsigned)f2bf(acc[r].w) << 16);
        uint2 pk; pk.x = lo; pk.y = hi;
        *(uint2*)(g2b + (size_t)n * NCLS + tx * 4) = pk;
        float vs = acc[r].x * av.x + acc[r].y * av.y + acc[r].z * av.z + acc[r].w * av.w;
        float vd = acc[r].x * dv.x + acc[r].y * dv.y + acc[r].z * dv.z + acc[r].w * dv.w;
        #pragma unroll
        for (int off = 4; off; off >>= 1) {
            vs += __shfl_down(vs, off);
            vd += __shfl_down(vd, off);
        }
        if (tx == 0) { a2s[n] = vs; a2d[n] = vd; }
    }
}

// ---------------- Layer 2 aggregation ----------------
__global__ __launch_bounds__(256) void agg2_kernel(
    const unsigned short* __restrict__ g2b, const float* __restrict__ a2s,
    const float* __restrict__ a2d, const int* __restrict__ offs,
    const int* __restrict__ oend, const int* __restrict__ csr,
    const float* __restrict__ b2, float* __restrict__ out, int N) {
    int d = blockIdx.x * 4 + (threadIdx.x >> 6);
    if (d >= N) return;
    int lane = threadIdx.x & 63;
    int beg = offs[d], end = oend[d];
    float ad = a2d[d];

    int q = lane >> 4, sub = lane & 15;
    int ch2 = sub * 2;
    float dn = 0.f;
    float2 ac = {0.f, 0.f};
    for (int i = beg; i < end; i += 16) {
        int i0 = i + q, i1 = i + 4 + q, i2 = i + 8 + q, i3 = i + 12 + q;
        bool v0 = i0 < end, v1 = i1 < end, v2 = i2 < end, v3 = i3 < end;
        int s0 = csr[v0 ? i0 : beg];
        int s1 = csr[v1 ? i1 : beg];
        int s2 = csr[v2 ? i2 : beg];
        int s3 = csr[v3 ? i3 : beg];
        float e0 = a2s[s0] + ad; e0 = e0 >= 0.f ? e0 : NS * e0;
        float e1 = a2s[s1] + ad; e1 = e1 >= 0.f ? e1 : NS * e1;
        float e2 = a2s[s2] + ad; e2 = e2 >= 0.f ? e2 : NS * e2;
        float e3 = a2s[s3] + ad; e3 = e3 >= 0.f ? e3 : NS * e3;
        float al0 = v0 ? __expf(e0) : 0.f;
        float al1 = v1 ? __expf(e1) : 0.f;
        float al2 = v2 ? __expf(e2) : 0.f;
        float al3 = v3 ? __expf(e3) : 0.f;
        dn += (al0 + al1) + (al2 + al3);
        unsigned int A = *(const unsigned int*)(g2b + (size_t)s0 * NCLS + ch2);
        unsigned int B = *(const unsigned int*)(g2b + (size_t)s1 * NCLS + ch2);
        unsigned int C = *(const unsigned int*)(g2b + (size_t)s2 * NCLS + ch2);
        unsigned int D = *(const unsigned int*)(g2b + (size_t)s3 * NCLS + ch2);
        float2 t;
        t = bf2x2(A); ac.x += t.x * al0; ac.y += t.y * al0;
        t = bf2x2(B); ac.x += t.x * al1; ac.y += t.y * al1;
        t = bf2x2(C); ac.x += t.x * al2; ac.y += t.y * al2;
        t = bf2x2(D); ac.x += t.x * al3; ac.y += t.y * al3;
    }
    dn += __shfl_xor(dn, 16);
    dn += __shfl_xor(dn, 32);
    #pragma unroll
    for (int off = 32; off >= 16; off >>= 1) {
        ac.x += __shfl_xor(ac.x, off);
        ac.y += __shfl_xor(ac.y, off);
    }
    float inv = 1.0f / (dn + 1e-16f);
    float2 bb = *(const float2*)(b2 + ch2);
    float v0 = ac.x * inv + bb.x;
    float v1 = ac.y * inv + bb.y;
    float m = fmaxf(v0, v1);
    #pragma unroll
    for (int off = 8; off; off >>= 1) m = fmaxf(m, __shfl_xor(m, off, 16));
    float e0 = __expf(v0 - m), e1 = __expf(v1 - m);
    float sm = e0 + e1;
    #pragma unroll
    for (int off = 8; off; off >>= 1) sm += __shfl_xor(sm, off, 16);
    if (q == 0) {
        float2 o; o.x = e0 / sm; o.y = e1 / sm;
        *(float2*)(out + (size_t)d * NCLS + ch2) = o;
    }
}

extern "C" void kernel_launch(void* const* d_in, const int* in_sizes, int n_in,
                              void* d_out, int out_size, void* d_ws, size_t ws_size,
                              hipStream_t stream) {
    const float* x   = (const float*)d_in[0];
    const int*   ei  = (const int*)d_in[1];
    const float* W1  = (const float*)d_in[2];
    const float* as1 = (const float*)d_in[3];
    const float* ad1 = (const float*)d_in[4];
    const float* b1  = (const float*)d_in[5];
    const float* W2  = (const float*)d_in[6];
    const float* as2 = (const float*)d_in[7];
    const float* ad2 = (const float*)d_in[8];
    const float* b2  = (const float*)d_in[9];
    float* out = (float*)d_out;

    int N = in_sizes[0] / FEAT;
    int E = in_sizes[1] / 2;
    int ET = E + N;
    int NB = (N + 255) >> 8;

    float* ws   = (float*)d_ws;
    unsigned short* h1b = (unsigned short*)ws;        // N*128 bf16
    float* hout = (float*)(h1b + (size_t)N * FEAT);   // N*128 f32
    unsigned short* g2b = (unsigned short*)(hout + (size_t)N * FEAT); // N*32 bf16
    float* a1s  = (float*)(g2b + (size_t)N * NCLS);   // N*4
    float* a1d  = a1s + (size_t)N * HEADS;            // N*4
    float* a2s  = a1d + (size_t)N * HEADS;            // N
    float* a2d  = a2s + N;                            // N
    int* offs   = (int*)(a2d + N);                    // N
    int* oend   = offs + N;                           // N
    unsigned int* binned = (unsigned int*)(oend + N); // 256*BSTRIDE (doubles as csr)
    int* gcursor = (int*)(binned + (size_t)256 * BSTRIDE); // 256

    int nchunks = (ET + CHUNK - 1) / CHUNK;

    cursor_init_kernel<<<1, 256, 0, stream>>>(gcursor);
    bin_kernel<<<nchunks, 256, 0, stream>>>(ei, E, ET, gcursor, binned);
    gemm1_kernel<<<(N + 63) / 64, 256, 0, stream>>>(x, W1, as1, ad1, h1b, a1s, a1d, N);
    csr_kernel<<<NB, 256, 0, stream>>>(binned, gcursor, offs, oend, N);

    const int* csr = (const int*)binned;
    agg1_kernel<<<(N + 3) / 4, 256, 0, stream>>>(h1b, a1s, a1d, offs, oend, csr, b1, hout, N);
    gemm2_kernel<<<(N + 127) / 128, 256, 0, stream>>>(hout, W2, as2, ad2, g2b, a2s, a2d, N);
    agg2_kernel<<<(N + 3) / 4, 256, 0, stream>>>(g2b, a2s, a2d, offs, oend, csr, b2, out, N);
}